// Round 10
// baseline (353.656 us; speedup 1.0000x reference)
//
#include <hip/hip_runtime.h>

#define S_LEN 2048
#define HID 4096
#define NH 32
#define NKV 8
#define HD 128
#define KVW 1024       // NKV*HD
#define NQKV 6144      // HID + 2*KVW

typedef _Float16 f16;
typedef _Float16 f16x8 __attribute__((ext_vector_type(8)));
typedef _Float16 f16x4 __attribute__((ext_vector_type(4)));
typedef float f32x4 __attribute__((ext_vector_type(4)));
typedef float f32x16 __attribute__((ext_vector_type(16)));
typedef unsigned int u32;
typedef u32 u32x4 __attribute__((ext_vector_type(4)));

__device__ __forceinline__ void gll16(const void* g, void* lds) {
  __builtin_amdgcn_global_load_lds((const __attribute__((address_space(1))) void*)g,
                                   (__attribute__((address_space(3))) void*)lds, 16, 0, 0);
}

template<int N> __device__ __forceinline__ void vmwait() {
  if constexpr (N == 0) asm volatile("s_waitcnt vmcnt(0)" ::: "memory");
  else if constexpr (N == 3) asm volatile("s_waitcnt vmcnt(3)" ::: "memory");
  else if constexpr (N == 4) asm volatile("s_waitcnt vmcnt(4)" ::: "memory");
  else static_assert(N == 0 || N == 3 || N == 4, "add vmcnt case");
}

// ---------------- cast hidden f32 -> f16 ----------------
__global__ void k_cast(const float* __restrict__ src, f16* __restrict__ dst) {
  size_t i = ((size_t)blockIdx.x * blockDim.x + threadIdx.x) * 8;
  float4 a = *(const float4*)(src + i);
  float4 b = *(const float4*)(src + i + 4);
  f16x8 o = { (f16)a.x, (f16)a.y, (f16)a.z, (f16)a.w,
              (f16)b.x, (f16)b.y, (f16)b.z, (f16)b.w };
  *(f16x8*)(dst + i) = o;
}

// ---------------- RoPE trig table: [S][64] float4 = (cos(2i), cos(2i+1), sin(2i), sin(2i+1))
__global__ void k_trig(float4* __restrict__ trig) {
  int id = blockIdx.x * blockDim.x + threadIdx.x;
  int s = id >> 6, i = id & 63;
  int j0 = 2 * i, j1 = 2 * i + 1;
  float f0 = powf(10000.f, -(float)(j0 & 63) / 64.f);
  float f1 = powf(10000.f, -(float)(j1 & 63) / 64.f);
  float a0 = (float)s * f0, a1 = (float)s * f1;
  trig[id] = make_float4(cosf(a0), cosf(a1), sinf(a0), sinf(a1));
}

// ---------------- fused weight transpose+cast, all 4 matrices, one launch ----------------
__global__ __launch_bounds__(256) void k_wprep(
    const float* __restrict__ wq, const float* __restrict__ wk,
    const float* __restrict__ wv, const float* __restrict__ wo,
    f16* __restrict__ Wt, f16* __restrict__ Wot)
{
  __shared__ float tile[32][33];
  int bid = blockIdx.x;
  const float* src; f16* dst; int N; int r;
  if (bid < 16384)      { src = wq; dst = Wt;                          N = 4096; r = bid; }
  else if (bid < 20480) { src = wk; dst = Wt + (size_t)4096 * 4096;    N = 1024; r = bid - 16384; }
  else if (bid < 24576) { src = wv; dst = Wt + (size_t)5120 * 4096;    N = 1024; r = bid - 20480; }
  else                  { src = wo; dst = Wot;                         N = 4096; r = bid - 24576; }
  int tpr = N >> 5;
  int kb = (r / tpr) * 32, nb = (r % tpr) * 32;
  int t = threadIdx.x;
  {
    int kl = t >> 3, ng = t & 7;
    float4 v = *(const float4*)(src + (size_t)(kb + kl) * N + nb + ng * 4);
    tile[kl][ng * 4 + 0] = v.x; tile[kl][ng * 4 + 1] = v.y;
    tile[kl][ng * 4 + 2] = v.z; tile[kl][ng * 4 + 3] = v.w;
  }
  __syncthreads();
  {
    int nl = t >> 3, kg = t & 7;
    f16x4 o = { (f16)tile[kg * 4 + 0][nl], (f16)tile[kg * 4 + 1][nl],
                (f16)tile[kg * 4 + 2][nl], (f16)tile[kg * 4 + 3][nl] };
    *(f16x4*)(dst + (size_t)(nb + nl) * HID + kb + kg * 4) = o;
  }
}

// ---------------- loose-sync GEMM, 32x32x16 MFMA fragments ----------------
// Same staging/ring/vmcnt structure as the R6-verified k_gemm4 (A dbuf t&1, B 3-ring
// t%3, stage A(t+1)+B(t+2) per tile, end-of-tile vmcnt(BCALLS) + one barrier).
// Changes vs k_gemm4:
//  * mfma_f32_32x32x16_f16: same operand bytes/lane, 2x MACs per instr, faster pipe
//    (m119: 2495 vs 2075 TF) and half the instruction count.
//    Operand layout [idx=lane&31][k=(lane>>5)*8+j]; C row=(reg&3)+8*(reg>>2)+4*hi,
//    col=lane&31 (both verified in-harness by k_attn since R3).
//  * swizzle: granule of row r permuted by (r&7)^((r>>3)&3) -> 32-lane frag reads
//    give 8 slots x 2 different-address lanes per quarter-wave = 2-way = free.
//  * XCD-aware block swizzle (grid%8==0): each XCD gets contiguous by-rows so the
//    shared A-panel is XCD-L2-resident.
// Geometry: waves WM x WN, wave tile (MB*32) x (NFB*32). BM=WM*MB*32, BN=WN*NFB*32.
extern __shared__ char smem[];

template<int MODE, int MB, int NFB, int WM, int WN>
__global__ __launch_bounds__(WM * WN * 64, 2) void k_gemm6(
    const f16* __restrict__ A, const f16* __restrict__ Bt,
    f16* __restrict__ Qr, f16* __restrict__ Kr, f16* __restrict__ Vt,
    const float4* __restrict__ trig, float* __restrict__ Cout)
{
  constexpr int NTHR = WM * WN * 64;
  constexpr int BM = WM * MB * 32;
  constexpr int BN = WN * NFB * 32;
  constexpr int ABYTES = BM * 128;
  constexpr int BBYTES = BN * 128;
  constexpr int RPC = NTHR / 8;          // rows per staging call
  constexpr int ACALLS = BM / RPC;
  constexpr int BCALLS = BN / RPC;
  constexpr int NT = 64;                 // K=4096 / BK=64

  const int tid = threadIdx.x, ln = tid & 63, w = tid >> 6;
  const int l31 = ln & 31, hi = ln >> 5;
  const int wr = w / WN, wc = w % WN;

  // XCD-aware block swizzle (bijective; grid size % 8 == 0)
  int bx, by;
  {
    int gx = gridDim.x;
    int lin = blockIdx.y * gx + blockIdx.x;
    int cpx = (gx * gridDim.y) >> 3;
    int swz = (lin & 7) * cpx + (lin >> 3);
    by = swz / gx; bx = swz % gx;
  }
  const int m0 = by * BM, n0 = bx * BN;

  // staging sources (tile 0): call c covers rows [c*RPC,(c+1)*RPC), 16B/thread
  const char* asrc[ACALLS];
  const char* bsrc[BCALLS];
  int adst[ACALLS > BCALLS ? ACALLS : BCALLS];
#pragma unroll
  for (int c = 0; c < ACALLS; ++c) {
    int r = c * RPC + (tid >> 3);
    int g = (tid & 7) ^ (r & 7) ^ ((r >> 3) & 3);
    asrc[c] = (const char*)A + ((size_t)(m0 + r) * HID + (size_t)g * 8) * 2;
    adst[c] = c * NTHR * 16 + tid * 16;
  }
#pragma unroll
  for (int c = 0; c < BCALLS; ++c) {
    int r = c * RPC + (tid >> 3);
    int g = (tid & 7) ^ (r & 7) ^ ((r >> 3) & 3);
    bsrc[c] = (const char*)Bt + ((size_t)(n0 + r) * HID + (size_t)g * 8) * 2;
  }

  char* const Bbase = smem + 2 * ABYTES;
  f32x16 acc[MB][NFB] = {};

  // prologue: A(0), B(0), B(1); leave B(1) in flight
#pragma unroll
  for (int c = 0; c < ACALLS; ++c) gll16(asrc[c], smem + adst[c]);
#pragma unroll
  for (int c = 0; c < BCALLS; ++c) gll16(bsrc[c], Bbase + adst[c]);
#pragma unroll
  for (int c = 0; c < BCALLS; ++c) gll16(bsrc[c] + 128, Bbase + BBYTES + adst[c]);
  vmwait<BCALLS>();
  __builtin_amdgcn_s_barrier();

  for (int t = 0; t < NT; ++t) {
    if (t + 1 < NT) {
      char* sa = smem + ((t + 1) & 1) * ABYTES;
#pragma unroll
      for (int c = 0; c < ACALLS; ++c) gll16(asrc[c] + (size_t)(t + 1) * 128, sa + adst[c]);
    }
    if (t + 2 < NT) {
      char* sb = Bbase + ((t + 2) % 3) * BBYTES;
#pragma unroll
      for (int c = 0; c < BCALLS; ++c) gll16(bsrc[c] + (size_t)(t + 2) * 128, sb + adst[c]);
    }
    const char* sa = smem + (t & 1) * ABYTES;
    const char* sb = Bbase + (t % 3) * BBYTES;
#pragma unroll
    for (int kk = 0; kk < 4; ++kk) {
      f16x8 af[MB], bf[NFB];
#pragma unroll
      for (int i = 0; i < MB; ++i) {
        int rl = wr * (MB * 32) + i * 32 + l31;
        int s = (kk * 2 + hi) ^ (rl & 7) ^ ((rl >> 3) & 3);
        af[i] = *(const f16x8*)(sa + rl * 128 + s * 16);
      }
#pragma unroll
      for (int n = 0; n < NFB; ++n) {
        int rb = wc * (NFB * 32) + n * 32 + l31;
        int s = (kk * 2 + hi) ^ (rb & 7) ^ ((rb >> 3) & 3);
        bf[n] = *(const f16x8*)(sb + rb * 128 + s * 16);
      }
      __builtin_amdgcn_s_setprio(1);
#pragma unroll
      for (int i = 0; i < MB; ++i)
#pragma unroll
        for (int n = 0; n < NFB; ++n)
          acc[i][n] = __builtin_amdgcn_mfma_f32_32x32x16_f16(af[i], bf[n], acc[i][n], 0, 0, 0);
      __builtin_amdgcn_s_setprio(0);
    }
    if (t < NT - 2)      vmwait<BCALLS>();
    else if (t == NT - 2) vmwait<0>();
    if (t < NT - 1) __builtin_amdgcn_s_barrier();
  }

  // ---- epilogue (32x32 C layout: col=lane&31, row=(reg&3)+8*(reg>>2)+4*hi) ----
#pragma unroll
  for (int i = 0; i < MB; ++i) {
#pragma unroll
    for (int n = 0; n < NFB; ++n) {
      f32x16 fr = acc[i][n];
      int col = n0 + wc * (NFB * 32) + n * 32 + l31;
      int mbase = m0 + wr * (MB * 32) + i * 32 + 4 * hi;
#pragma unroll
      for (int q = 0; q < 4; ++q) {
        int mr = mbase + q * 8;
        if (MODE == 0) {
          if (col < HID + KVW) {         // Q or K region -> RoPE
            int d = col & 127;
#pragma unroll
            for (int r = 0; r < 4; ++r) {
              float v = fr[q * 4 + r];
              float p = __shfl_xor(v, 1);
              float4 tc = trig[(size_t)(mr + r) * 64 + (d >> 1)];
              float cv = (d & 1) ? tc.y : tc.x;
              float sv = (d & 1) ? tc.w : tc.z;
              float o = v * cv + ((d & 1) ? p : -p) * sv;
              if (col < HID) Qr[(size_t)(mr + r) * HID + col] = (f16)o;
              else           Kr[(size_t)(mr + r) * KVW + (col - HID)] = (f16)o;
            }
          } else {                        // V region -> transposed store Vt[n][s]
            int nv = col - (HID + KVW);
            f16x4 o4 = { (f16)fr[q * 4 + 0], (f16)fr[q * 4 + 1],
                         (f16)fr[q * 4 + 2], (f16)fr[q * 4 + 3] };
            *(f16x4*)(Vt + (size_t)nv * S_LEN + mr) = o4;
          }
        } else {
#pragma unroll
          for (int r = 0; r < 4; ++r)
            Cout[(size_t)(mr + r) * HID + col] = fr[q * 4 + r];
        }
      }
    }
  }
}

// ---------------- flash attention, causal, GQA — swapped-QK^T 32x32 MFMA ----------------
#define KBYTES (64 * 128 * 2)   // 16KB K tile [64 kv][128 hd]
#define VBYTES (128 * 64 * 2)   // 16KB V tile [128 d][64 kv]

__global__ __launch_bounds__(256, 2) void k_attn(
    const f16* __restrict__ Qr, const f16* __restrict__ Kr, const f16* __restrict__ Vt,
    f16* __restrict__ AO)
{
  int bid = blockIdx.x;
  int h, c;
  if (bid < 256) { h = bid >> 3; c = bid & 7; }
  else           { int t = bid - 256; h = t >> 3; c = 15 - (t & 7); }
  const int hkv = h >> 2;
  const int q0c = c * 128;
  const int NT = 2 * c + 2;

  __shared__ char KV[2][KBYTES + VBYTES];

  const int tid = threadIdx.x;
  const int ln = tid & 63, w = tid >> 6;
  const int q = ln & 31;
  const int hi = ln >> 5;
  const int qg = q0c + w * 32 + q;

  size_t ksrc[4], vsrc[4];
  int kdo[4], vdo[4];
#pragma unroll
  for (int j = 0; j < 4; ++j) {
    int kc = w * 4 + j;
    int kr = kc * 4 + (ln >> 4);
    ksrc[j] = ((size_t)kr * KVW + hkv * HD) * 2 + (size_t)(((ln & 15) ^ (kr & 7)) * 16);
    kdo[j] = kc * 1024;
    int vc = w * 4 + j;
    int d = vc * 8 + (ln >> 3);
    vsrc[j] = ((size_t)(hkv * HD + d) * S_LEN) * 2 + (size_t)(((ln & 7) ^ (d & 7)) * 16);
    vdo[j] = KBYTES + vc * 1024;
  }

  f16x8 qf[8];
  {
    const f16* qrow = Qr + (size_t)qg * HID + h * HD + hi * 8;
#pragma unroll
    for (int ks = 0; ks < 8; ++ks) qf[ks] = *(const f16x8*)(qrow + ks * 16);
  }

  f32x16 ot[4] = {};
  float m2 = -3.0e38f, l = 0.f;
  const float K2 = 0.12753256471f;  // log2(e)/sqrt(128)

  int buf = 0;
#pragma unroll
  for (int j = 0; j < 4; ++j) {
    gll16((const char*)Kr + ksrc[j], &KV[0][kdo[j]]);
    gll16((const char*)Vt + vsrc[j], &KV[0][vdo[j]]);
  }

  for (int jt = 0; jt < NT; ++jt) {
    __syncthreads();
    if (jt + 1 < NT) {
      size_t ko = (size_t)(jt + 1) * 64 * KVW * 2;
      size_t vo = (size_t)(jt + 1) * 64 * 2;
#pragma unroll
      for (int j = 0; j < 4; ++j) {
        gll16((const char*)Kr + ksrc[j] + ko, &KV[buf ^ 1][kdo[j]]);
        gll16((const char*)Vt + vsrc[j] + vo, &KV[buf ^ 1][vdo[j]]);
      }
    }
    const int j0 = jt * 64;
    if (j0 <= q0c + w * 32 + 31) {
      const f16* Kb = (const f16*)&KV[buf][0];
      const f16* Vb = (const f16*)&KV[buf][KBYTES];
      f32x16 s0 = {}, s1 = {};
#pragma unroll
      for (int ks = 0; ks < 8; ++ks) {
        int cc = ((ks * 2 + hi) ^ (q & 7)) * 8;
        f16x8 k0 = *(const f16x8*)(Kb + q * 128 + cc);
        f16x8 k1 = *(const f16x8*)(Kb + (q + 32) * 128 + cc);
        s0 = __builtin_amdgcn_mfma_f32_32x32x16_f16(k0, qf[ks], s0, 0, 0, 0);
        s1 = __builtin_amdgcn_mfma_f32_32x32x16_f16(k1, qf[ks], s1, 0, 0, 0);
      }
      const bool nm = (j0 + 63 > q0c + w * 32);
      float p0[16], p1[16];
      float mx = -3.0e38f;
#pragma unroll
      for (int r = 0; r < 16; ++r) {
        float a = s0[r], b = s1[r];
        if (nm) {
          int kvb = j0 + (r & 3) + 8 * (r >> 2) + 4 * hi;
          if (kvb > qg) a = -3.0e38f;
          if (kvb + 32 > qg) b = -3.0e38f;
        }
        p0[r] = a; p1[r] = b;
        mx = fmaxf(mx, fmaxf(a, b));
      }
      mx = fmaxf(mx, __shfl_xor(mx, 32));
      float m2c = mx * K2;
      int defer = (m2c <= m2 + 11.0f);
      if (!__all(defer)) {
        float m2n = fmaxf(m2, m2c);
        float corr = exp2f(m2 - m2n);
        m2 = m2n; l *= corr;
#pragma unroll
        for (int t = 0; t < 4; ++t)
#pragma unroll
          for (int r = 0; r < 16; ++r) ot[t][r] *= corr;
      }
      float sum = 0.f;
#pragma unroll
      for (int r = 0; r < 16; ++r) {
        p0[r] = exp2f(__builtin_fmaf(p0[r], K2, -m2));
        p1[r] = exp2f(__builtin_fmaf(p1[r], K2, -m2));
        sum += p0[r] + p1[r];
      }
      l += sum + __shfl_xor(sum, 32);
      u32 pw0[8], pw1[8];
#pragma unroll
      for (int t = 0; t < 8; ++t) {
        pw0[t] = __builtin_bit_cast(u32, __builtin_amdgcn_cvt_pkrtz(p0[2 * t], p0[2 * t + 1]));
        pw1[t] = __builtin_bit_cast(u32, __builtin_amdgcn_cvt_pkrtz(p1[2 * t], p1[2 * t + 1]));
      }
      f16x8 pf[4];
#pragma unroll
      for (int ch = 0; ch < 2; ++ch) {
        const u32* pw = ch ? pw1 : pw0;
        u32 sx[8];
#pragma unroll
        for (int t = 0; t < 8; ++t) sx[t] = (u32)__shfl_xor((int)pw[t], 32);
        u32x4 fa = { hi ? sx[2] : pw[0], hi ? sx[3] : pw[1],
                     hi ? pw[2] : sx[0], hi ? pw[3] : sx[1] };
        u32x4 fb = { hi ? sx[6] : pw[4], hi ? sx[7] : pw[5],
                     hi ? pw[6] : sx[4], hi ? pw[7] : sx[5] };
        pf[ch * 2 + 0] = __builtin_bit_cast(f16x8, fa);
        pf[ch * 2 + 1] = __builtin_bit_cast(f16x8, fb);
      }
#pragma unroll
      for (int dt = 0; dt < 4; ++dt) {
        int d = dt * 32 + q;
#pragma unroll
        for (int f = 0; f < 4; ++f) {
          f16x8 vf = *(const f16x8*)(Vb + d * 64 + (((f * 2 + hi) ^ (q & 7)) * 8));
          ot[dt] = __builtin_amdgcn_mfma_f32_32x32x16_f16(vf, pf[f], ot[dt], 0, 0, 0);
        }
      }
    }
    buf ^= 1;
  }

  __syncthreads();
  char* scr = &KV[0][0] + w * 8192;
  float inv = 1.f / l;
#pragma unroll
  for (int dt = 0; dt < 4; ++dt) {
#pragma unroll
    for (int rg = 0; rg < 4; ++rg) {
      u32 wa = __builtin_bit_cast(u32, __builtin_amdgcn_cvt_pkrtz(ot[dt][rg * 4 + 0] * inv, ot[dt][rg * 4 + 1] * inv));
      u32 wb = __builtin_bit_cast(u32, __builtin_amdgcn_cvt_pkrtz(ot[dt][rg * 4 + 2] * inv, ot[dt][rg * 4 + 3] * inv));
      int byte = q * 256 + (((dt * 4 + rg) ^ (q & 7)) * 16) + hi * 8;
      u32* p = (u32*)(scr + byte);
      p[0] = wa; p[1] = wb;
    }
  }
  asm volatile("s_waitcnt lgkmcnt(0)" ::: "memory");
#pragma unroll
  for (int ps = 0; ps < 8; ++ps) {
    int qr = ps * 4 + (ln >> 4);
    int ck = (ln & 15) ^ (qr & 7);
    f16x8 v = *(const f16x8*)(scr + qr * 256 + ck * 16);
    *(f16x8*)(AO + (size_t)(q0c + w * 32 + qr) * HID + h * HD + (ln & 15) * 8) = v;
  }
}

extern "C" void kernel_launch(void* const* d_in, const int* in_sizes, int n_in,
                              void* d_out, int out_size, void* d_ws, size_t ws_size,
                              hipStream_t stream) {
  const float* hs = (const float*)d_in[0];
  // d_in[1] = attention_mask (pure causal; handled analytically)
  const float* wq = (const float*)d_in[2];
  const float* wk = (const float*)d_in[3];
  const float* wv = (const float*)d_in[4];
  const float* wo = (const float*)d_in[5];
  float* out = (float*)d_out;

  char* ws = (char*)d_ws;
  size_t off = 0;
  auto alloc = [&](size_t b) { char* p = ws + off; off += (b + 255) & ~(size_t)255; return p; };
  f16* Hh   = (f16*)alloc((size_t)S_LEN * HID * 2);
  f16* Wt   = (f16*)alloc((size_t)NQKV * HID * 2);
  float4* trig = (float4*)alloc((size_t)S_LEN * 64 * sizeof(float4));
  f16* Qrp  = (f16*)alloc((size_t)S_LEN * HID * 2);
  f16* Krp  = (f16*)alloc((size_t)S_LEN * KVW * 2);
  f16* Vtp  = (f16*)alloc((size_t)KVW * S_LEN * 2);
  f16* AO   = (f16*)alloc((size_t)S_LEN * HID * 2);
  f16* Wot  = (f16*)alloc((size_t)HID * HID * 2);

  // gemm<0>: 8 waves 4Mx2N, wave 64x96, BM=256 BN=192, LDS 2*32K + 3*24K = 136KB
  hipFuncSetAttribute((const void*)k_gemm6<0, 2, 3, 4, 2>,
                      hipFuncAttributeMaxDynamicSharedMemorySize, 139264);
  // gemm<1>: 4 waves 2x2, wave 64x64, BM=BN=128, LDS 2*16K + 3*16K = 80KB (2 blk/CU)
  hipFuncSetAttribute((const void*)k_gemm6<1, 2, 2, 2, 2>,
                      hipFuncAttributeMaxDynamicSharedMemorySize, 81920);

  k_cast<<<(S_LEN * HID) / (256 * 8), 256, 0, stream>>>(hs, Hh);
  k_trig<<<(S_LEN * 64) / 256, 256, 0, stream>>>(trig);
  k_wprep<<<40960, 256, 0, stream>>>(wq, wk, wv, wo, Wt, Wot);
  k_gemm6<0, 2, 3, 4, 2><<<dim3(NQKV / 192, S_LEN / 256), 512, 139264, stream>>>(
      Hh, Wt, Qrp, Krp, Vtp, trig, nullptr);
  k_attn<<<dim3(512), 256, 0, stream>>>(Qrp, Krp, Vtp, AO);
  k_gemm6<1, 2, 2, 2, 2><<<dim3(HID / 128, S_LEN / 128), 256, 81920, stream>>>(
      AO, Wot, nullptr, nullptr, nullptr, nullptr, out);
}

// Round 11
// 330.064 us; speedup vs baseline: 1.0715x; 1.0715x over previous
//
#include <hip/hip_runtime.h>

#define S_LEN 2048
#define HID 4096
#define NH 32
#define NKV 8
#define HD 128
#define KVW 1024       // NKV*HD
#define NQKV 6144      // HID + 2*KVW

typedef _Float16 f16;
typedef _Float16 f16x8 __attribute__((ext_vector_type(8)));
typedef _Float16 f16x4 __attribute__((ext_vector_type(4)));
typedef float f32x4 __attribute__((ext_vector_type(4)));
typedef float f32x16 __attribute__((ext_vector_type(16)));
typedef unsigned int u32;
typedef u32 u32x4 __attribute__((ext_vector_type(4)));

__device__ __forceinline__ void gll16(const void* g, void* lds) {
  __builtin_amdgcn_global_load_lds((const __attribute__((address_space(1))) void*)g,
                                   (__attribute__((address_space(3))) void*)lds, 16, 0, 0);
}

template<int N> __device__ __forceinline__ void vmwait() {
  if constexpr (N == 0) asm volatile("s_waitcnt vmcnt(0)" ::: "memory");
  else if constexpr (N == 3) asm volatile("s_waitcnt vmcnt(3)" ::: "memory");
  else if constexpr (N == 4) asm volatile("s_waitcnt vmcnt(4)" ::: "memory");
  else static_assert(N == 0 || N == 3 || N == 4, "add vmcnt case");
}

// ---------------- cast hidden f32 -> f16 ----------------
__global__ void k_cast(const float* __restrict__ src, f16* __restrict__ dst) {
  size_t i = ((size_t)blockIdx.x * blockDim.x + threadIdx.x) * 8;
  float4 a = *(const float4*)(src + i);
  float4 b = *(const float4*)(src + i + 4);
  f16x8 o = { (f16)a.x, (f16)a.y, (f16)a.z, (f16)a.w,
              (f16)b.x, (f16)b.y, (f16)b.z, (f16)b.w };
  *(f16x8*)(dst + i) = o;
}

// ---------------- RoPE trig table: [S][64] float4 = (cos(2i), cos(2i+1), sin(2i), sin(2i+1))
__global__ void k_trig(float4* __restrict__ trig) {
  int id = blockIdx.x * blockDim.x + threadIdx.x;
  int s = id >> 6, i = id & 63;
  int j0 = 2 * i, j1 = 2 * i + 1;
  float f0 = powf(10000.f, -(float)(j0 & 63) / 64.f);
  float f1 = powf(10000.f, -(float)(j1 & 63) / 64.f);
  float a0 = (float)s * f0, a1 = (float)s * f1;
  trig[id] = make_float4(cosf(a0), cosf(a1), sinf(a0), sinf(a1));
}

// ---------------- fused weight transpose+cast, all 4 matrices, one launch ----------------
__global__ __launch_bounds__(256) void k_wprep(
    const float* __restrict__ wq, const float* __restrict__ wk,
    const float* __restrict__ wv, const float* __restrict__ wo,
    f16* __restrict__ Wt, f16* __restrict__ Wot)
{
  __shared__ float tile[32][33];
  int bid = blockIdx.x;
  const float* src; f16* dst; int N; int r;
  if (bid < 16384)      { src = wq; dst = Wt;                          N = 4096; r = bid; }
  else if (bid < 20480) { src = wk; dst = Wt + (size_t)4096 * 4096;    N = 1024; r = bid - 16384; }
  else if (bid < 24576) { src = wv; dst = Wt + (size_t)5120 * 4096;    N = 1024; r = bid - 20480; }
  else                  { src = wo; dst = Wot;                         N = 4096; r = bid - 24576; }
  int tpr = N >> 5;
  int kb = (r / tpr) * 32, nb = (r % tpr) * 32;
  int t = threadIdx.x;
  {
    int kl = t >> 3, ng = t & 7;
    float4 v = *(const float4*)(src + (size_t)(kb + kl) * N + nb + ng * 4);
    tile[kl][ng * 4 + 0] = v.x; tile[kl][ng * 4 + 1] = v.y;
    tile[kl][ng * 4 + 2] = v.z; tile[kl][ng * 4 + 3] = v.w;
  }
  __syncthreads();
  {
    int nl = t >> 3, kg = t & 7;
    f16x4 o = { (f16)tile[kg * 4 + 0][nl], (f16)tile[kg * 4 + 1][nl],
                (f16)tile[kg * 4 + 2][nl], (f16)tile[kg * 4 + 3][nl] };
    *(f16x4*)(dst + (size_t)(nb + nl) * HID + kb + kg * 4) = o;
  }
}

// ---------------- loose-sync deep-prefetch GEMM (R6/R9-verified) + XCD-COMPACT mapping ----
// R11 change (ONLY): block -> (bx,by) mapping. Default dispatch round-robins XCDs
// (XCD = b&7). We give each XCD a COMPACT 4bx x 8by sub-grid so its 32 co-resident
// blocks share 4 B-panels (L2-hit 7x) and 8 A-panels (L2-hit 3x); active K-slice
// working set ~350 KB << 4 MB per-XCD L2. (R10's swizzle did the OPPOSITE - each XCD
// got all 32 bx -> 48 MB B working set -> FETCH doubled to 206 MB.)
// Everything else byte-identical to R9: A dbuf t&1 + B 3-ring t%3, stage A(t+1)+B(t+2)
// per tile, end-of-tile vmcnt(BCALLS) (never 0 steady-state) + ONE barrier; swizzle
// granule g of row r at slot g^(r&7), read (ks*4+lg)^(r&7) - measured 0 conflicts.
extern __shared__ char smem[];

template<int MODE, int MF, int NF, int WM, int WN>
__global__ __launch_bounds__(WM * WN * 64, 2) void k_gemm4(
    const f16* __restrict__ A, const f16* __restrict__ Bt,
    f16* __restrict__ Qr, f16* __restrict__ Kr, f16* __restrict__ Vt,
    const float4* __restrict__ trig, float* __restrict__ Cout)
{
  constexpr int NTHR = WM * WN * 64;
  constexpr int BM = WM * MF * 16;
  constexpr int BN = WN * NF * 16;
  constexpr int ABYTES = BM * 128;
  constexpr int BBYTES = BN * 128;
  constexpr int RPC = NTHR / 8;          // rows per staging call
  constexpr int ACALLS = BM / RPC;
  constexpr int BCALLS = BN / RPC;
  constexpr int NT = 64;                 // K=4096 / BK=64

  const int tid = threadIdx.x, ln = tid & 63, w = tid >> 6;
  const int la = ln & 15, lg = ln >> 4;
  const int wr = w / WN, wc = w % WN;

  // XCD-compact block mapping (grid.x assumed 32, grid.x*grid.y % 8 == 0)
  int bx, by;
  {
    int b = blockIdx.y * gridDim.x + blockIdx.x;
    int cx = gridDim.x >> 3;           // bx-chunk width per XCD (= 4 here)
    int xcd = b & 7, rr = b >> 3;
    bx = xcd * cx + (rr % cx);
    by = rr / cx;
  }
  const int m0 = by * BM, n0 = bx * BN;

  const char* asrc[ACALLS];
  const char* bsrc[BCALLS];
  int adst[ACALLS > BCALLS ? ACALLS : BCALLS];
#pragma unroll
  for (int c = 0; c < ACALLS; ++c) {
    int r = c * RPC + (tid >> 3);
    int g = (tid & 7) ^ (r & 7);
    asrc[c] = (const char*)A + ((size_t)(m0 + r) * HID + (size_t)g * 8) * 2;
    adst[c] = c * NTHR * 16 + tid * 16;
  }
#pragma unroll
  for (int c = 0; c < BCALLS; ++c) {
    int r = c * RPC + (tid >> 3);
    int g = (tid & 7) ^ (r & 7);
    bsrc[c] = (const char*)Bt + ((size_t)(n0 + (r >= BN ? r - BN : r)) * HID + (size_t)g * 8) * 2;
  }

  char* const Bbase = smem + 2 * ABYTES;
  f32x4 acc[MF][NF] = {};

  // prologue: A(0), B(0), B(1); leave B(1) in flight
#pragma unroll
  for (int c = 0; c < ACALLS; ++c) gll16(asrc[c], smem + adst[c]);
#pragma unroll
  for (int c = 0; c < BCALLS; ++c) gll16(bsrc[c], Bbase + adst[c]);
#pragma unroll
  for (int c = 0; c < BCALLS; ++c) gll16(bsrc[c] + 128, Bbase + BBYTES + adst[c]);
  vmwait<BCALLS>();
  __builtin_amdgcn_s_barrier();

  for (int t = 0; t < NT; ++t) {
    if (t + 1 < NT) {
      char* sa = smem + ((t + 1) & 1) * ABYTES;
#pragma unroll
      for (int c = 0; c < ACALLS; ++c) gll16(asrc[c] + (size_t)(t + 1) * 128, sa + adst[c]);
    }
    if (t + 2 < NT) {
      char* sb = Bbase + ((t + 2) % 3) * BBYTES;
#pragma unroll
      for (int c = 0; c < BCALLS; ++c) gll16(bsrc[c] + (size_t)(t + 2) * 128, sb + adst[c]);
    }
    const char* sa = smem + (t & 1) * ABYTES;
    const char* sb = Bbase + (t % 3) * BBYTES;
#pragma unroll
    for (int ks = 0; ks < 2; ++ks) {
      f16x8 af[MF], bf[NF];
#pragma unroll
      for (int i = 0; i < MF; ++i) {
        int rl = wr * MF * 16 + i * 16 + la;
        af[i] = *(const f16x8*)(sa + rl * 128 + (((ks * 4 + lg) ^ (rl & 7)) * 16));
      }
#pragma unroll
      for (int n = 0; n < NF; ++n) {
        int rb = wc * NF * 16 + n * 16 + la;
        bf[n] = *(const f16x8*)(sb + rb * 128 + (((ks * 4 + lg) ^ (rb & 7)) * 16));
      }
      __builtin_amdgcn_s_setprio(1);
#pragma unroll
      for (int i = 0; i < MF; ++i)
#pragma unroll
        for (int n = 0; n < NF; ++n)
          acc[i][n] = __builtin_amdgcn_mfma_f32_16x16x32_f16(af[i], bf[n], acc[i][n], 0, 0, 0);
      __builtin_amdgcn_s_setprio(0);
    }
    if (t < NT - 2)      vmwait<BCALLS>();
    else if (t == NT - 2) vmwait<0>();
    if (t < NT - 1) __builtin_amdgcn_s_barrier();
  }

  // ---- epilogue ----
#pragma unroll
  for (int mi = 0; mi < MF; ++mi) {
#pragma unroll
    for (int nf = 0; nf < NF; ++nf) {
      f32x4 fr = acc[mi][nf];
      int n = n0 + wc * NF * 16 + nf * 16 + la;
      int mr = m0 + wr * MF * 16 + mi * 16 + lg * 4;
      if (MODE == 0) {
        if (n < HID + KVW) {           // Q or K region -> RoPE
          int d = n & 127;
#pragma unroll
          for (int r = 0; r < 4; ++r) {
            float v = fr[r];
            float p = __shfl_xor(v, 1);
            float4 tc = trig[(size_t)(mr + r) * 64 + (d >> 1)];
            float cv = (d & 1) ? tc.y : tc.x;
            float sv = (d & 1) ? tc.w : tc.z;
            float o = v * cv + ((d & 1) ? p : -p) * sv;
            if (n < HID) Qr[(size_t)(mr + r) * HID + n] = (f16)o;
            else         Kr[(size_t)(mr + r) * KVW + (n - HID)] = (f16)o;
          }
        } else {                        // V region -> transposed store Vt[n][s]
          int nv = n - (HID + KVW);
          f16x4 o4 = { (f16)fr[0], (f16)fr[1], (f16)fr[2], (f16)fr[3] };
          *(f16x4*)(Vt + (size_t)nv * S_LEN + mr) = o4;
        }
      } else {
#pragma unroll
        for (int r = 0; r < 4; ++r)
          Cout[(size_t)(mr + r) * HID + n] = fr[r];
      }
    }
  }
}

// ---------------- flash attention, causal, GQA — swapped-QK^T 32x32 MFMA ----------------
#define KBYTES (64 * 128 * 2)   // 16KB K tile [64 kv][128 hd]
#define VBYTES (128 * 64 * 2)   // 16KB V tile [128 d][64 kv]

__global__ __launch_bounds__(256, 2) void k_attn(
    const f16* __restrict__ Qr, const f16* __restrict__ Kr, const f16* __restrict__ Vt,
    f16* __restrict__ AO)
{
  int bid = blockIdx.x;
  int h, c;
  if (bid < 256) { h = bid >> 3; c = bid & 7; }
  else           { int t = bid - 256; h = t >> 3; c = 15 - (t & 7); }
  const int hkv = h >> 2;
  const int q0c = c * 128;
  const int NT = 2 * c + 2;

  __shared__ char KV[2][KBYTES + VBYTES];

  const int tid = threadIdx.x;
  const int ln = tid & 63, w = tid >> 6;
  const int q = ln & 31;
  const int hi = ln >> 5;
  const int qg = q0c + w * 32 + q;

  size_t ksrc[4], vsrc[4];
  int kdo[4], vdo[4];
#pragma unroll
  for (int j = 0; j < 4; ++j) {
    int kc = w * 4 + j;
    int kr = kc * 4 + (ln >> 4);
    ksrc[j] = ((size_t)kr * KVW + hkv * HD) * 2 + (size_t)(((ln & 15) ^ (kr & 7)) * 16);
    kdo[j] = kc * 1024;
    int vc = w * 4 + j;
    int d = vc * 8 + (ln >> 3);
    vsrc[j] = ((size_t)(hkv * HD + d) * S_LEN) * 2 + (size_t)(((ln & 7) ^ (d & 7)) * 16);
    vdo[j] = KBYTES + vc * 1024;
  }

  f16x8 qf[8];
  {
    const f16* qrow = Qr + (size_t)qg * HID + h * HD + hi * 8;
#pragma unroll
    for (int ks = 0; ks < 8; ++ks) qf[ks] = *(const f16x8*)(qrow + ks * 16);
  }

  f32x16 ot[4] = {};
  float m2 = -3.0e38f, l = 0.f;
  const float K2 = 0.12753256471f;  // log2(e)/sqrt(128)

  int buf = 0;
#pragma unroll
  for (int j = 0; j < 4; ++j) {
    gll16((const char*)Kr + ksrc[j], &KV[0][kdo[j]]);
    gll16((const char*)Vt + vsrc[j], &KV[0][vdo[j]]);
  }

  for (int jt = 0; jt < NT; ++jt) {
    __syncthreads();
    if (jt + 1 < NT) {
      size_t ko = (size_t)(jt + 1) * 64 * KVW * 2;
      size_t vo = (size_t)(jt + 1) * 64 * 2;
#pragma unroll
      for (int j = 0; j < 4; ++j) {
        gll16((const char*)Kr + ksrc[j] + ko, &KV[buf ^ 1][kdo[j]]);
        gll16((const char*)Vt + vsrc[j] + vo, &KV[buf ^ 1][vdo[j]]);
      }
    }
    const int j0 = jt * 64;
    if (j0 <= q0c + w * 32 + 31) {
      const f16* Kb = (const f16*)&KV[buf][0];
      const f16* Vb = (const f16*)&KV[buf][KBYTES];
      f32x16 s0 = {}, s1 = {};
#pragma unroll
      for (int ks = 0; ks < 8; ++ks) {
        int cc = ((ks * 2 + hi) ^ (q & 7)) * 8;
        f16x8 k0 = *(const f16x8*)(Kb + q * 128 + cc);
        f16x8 k1 = *(const f16x8*)(Kb + (q + 32) * 128 + cc);
        s0 = __builtin_amdgcn_mfma_f32_32x32x16_f16(k0, qf[ks], s0, 0, 0, 0);
        s1 = __builtin_amdgcn_mfma_f32_32x32x16_f16(k1, qf[ks], s1, 0, 0, 0);
      }
      const bool nm = (j0 + 63 > q0c + w * 32);
      float p0[16], p1[16];
      float mx = -3.0e38f;
#pragma unroll
      for (int r = 0; r < 16; ++r) {
        float a = s0[r], b = s1[r];
        if (nm) {
          int kvb = j0 + (r & 3) + 8 * (r >> 2) + 4 * hi;
          if (kvb > qg) a = -3.0e38f;
          if (kvb + 32 > qg) b = -3.0e38f;
        }
        p0[r] = a; p1[r] = b;
        mx = fmaxf(mx, fmaxf(a, b));
      }
      mx = fmaxf(mx, __shfl_xor(mx, 32));
      float m2c = mx * K2;
      int defer = (m2c <= m2 + 11.0f);
      if (!__all(defer)) {
        float m2n = fmaxf(m2, m2c);
        float corr = exp2f(m2 - m2n);
        m2 = m2n; l *= corr;
#pragma unroll
        for (int t = 0; t < 4; ++t)
#pragma unroll
          for (int r = 0; r < 16; ++r) ot[t][r] *= corr;
      }
      float sum = 0.f;
#pragma unroll
      for (int r = 0; r < 16; ++r) {
        p0[r] = exp2f(__builtin_fmaf(p0[r], K2, -m2));
        p1[r] = exp2f(__builtin_fmaf(p1[r], K2, -m2));
        sum += p0[r] + p1[r];
      }
      l += sum + __shfl_xor(sum, 32);
      u32 pw0[8], pw1[8];
#pragma unroll
      for (int t = 0; t < 8; ++t) {
        pw0[t] = __builtin_bit_cast(u32, __builtin_amdgcn_cvt_pkrtz(p0[2 * t], p0[2 * t + 1]));
        pw1[t] = __builtin_bit_cast(u32, __builtin_amdgcn_cvt_pkrtz(p1[2 * t], p1[2 * t + 1]));
      }
      f16x8 pf[4];
#pragma unroll
      for (int ch = 0; ch < 2; ++ch) {
        const u32* pw = ch ? pw1 : pw0;
        u32 sx[8];
#pragma unroll
        for (int t = 0; t < 8; ++t) sx[t] = (u32)__shfl_xor((int)pw[t], 32);
        u32x4 fa = { hi ? sx[2] : pw[0], hi ? sx[3] : pw[1],
                     hi ? pw[2] : sx[0], hi ? pw[3] : sx[1] };
        u32x4 fb = { hi ? sx[6] : pw[4], hi ? sx[7] : pw[5],
                     hi ? pw[6] : sx[4], hi ? pw[7] : sx[5] };
        pf[ch * 2 + 0] = __builtin_bit_cast(f16x8, fa);
        pf[ch * 2 + 1] = __builtin_bit_cast(f16x8, fb);
      }
#pragma unroll
      for (int dt = 0; dt < 4; ++dt) {
        int d = dt * 32 + q;
#pragma unroll
        for (int f = 0; f < 4; ++f) {
          f16x8 vf = *(const f16x8*)(Vb + d * 64 + (((f * 2 + hi) ^ (q & 7)) * 8));
          ot[dt] = __builtin_amdgcn_mfma_f32_32x32x16_f16(vf, pf[f], ot[dt], 0, 0, 0);
        }
      }
    }
    buf ^= 1;
  }

  __syncthreads();
  char* scr = &KV[0][0] + w * 8192;
  float inv = 1.f / l;
#pragma unroll
  for (int dt = 0; dt < 4; ++dt) {
#pragma unroll
    for (int rg = 0; rg < 4; ++rg) {
      u32 wa = __builtin_bit_cast(u32, __builtin_amdgcn_cvt_pkrtz(ot[dt][rg * 4 + 0] * inv, ot[dt][rg * 4 + 1] * inv));
      u32 wb = __builtin_bit_cast(u32, __builtin_amdgcn_cvt_pkrtz(ot[dt][rg * 4 + 2] * inv, ot[dt][rg * 4 + 3] * inv));
      int byte = q * 256 + (((dt * 4 + rg) ^ (q & 7)) * 16) + hi * 8;
      u32* p = (u32*)(scr + byte);
      p[0] = wa; p[1] = wb;
    }
  }
  asm volatile("s_waitcnt lgkmcnt(0)" ::: "memory");
#pragma unroll
  for (int ps = 0; ps < 8; ++ps) {
    int qr = ps * 4 + (ln >> 4);
    int ck = (ln & 15) ^ (qr & 7);
    f16x8 v = *(const f16x8*)(scr + qr * 256 + ck * 16);
    *(f16x8*)(AO + (size_t)(q0c + w * 32 + qr) * HID + h * HD + (ln & 15) * 8) = v;
  }
}

extern "C" void kernel_launch(void* const* d_in, const int* in_sizes, int n_in,
                              void* d_out, int out_size, void* d_ws, size_t ws_size,
                              hipStream_t stream) {
  const float* hs = (const float*)d_in[0];
  // d_in[1] = attention_mask (pure causal; handled analytically)
  const float* wq = (const float*)d_in[2];
  const float* wk = (const float*)d_in[3];
  const float* wv = (const float*)d_in[4];
  const float* wo = (const float*)d_in[5];
  float* out = (float*)d_out;

  char* ws = (char*)d_ws;
  size_t off = 0;
  auto alloc = [&](size_t b) { char* p = ws + off; off += (b + 255) & ~(size_t)255; return p; };
  f16* Hh   = (f16*)alloc((size_t)S_LEN * HID * 2);
  f16* Wt   = (f16*)alloc((size_t)NQKV * HID * 2);
  float4* trig = (float4*)alloc((size_t)S_LEN * 64 * sizeof(float4));
  f16* Qrp  = (f16*)alloc((size_t)S_LEN * HID * 2);
  f16* Krp  = (f16*)alloc((size_t)S_LEN * KVW * 2);
  f16* Vtp  = (f16*)alloc((size_t)KVW * S_LEN * 2);
  f16* AO   = (f16*)alloc((size_t)S_LEN * HID * 2);
  f16* Wot  = (f16*)alloc((size_t)HID * HID * 2);

  // gemm<0>: 8 waves 2x4, wave 128x48, BM=256 BN=192, LDS 2*32K + 3*24K = 136KB
  hipFuncSetAttribute((const void*)k_gemm4<0, 8, 3, 2, 4>,
                      hipFuncAttributeMaxDynamicSharedMemorySize, 139264);
  // gemm<1>: 4 waves 2x2, wave 64x64, BM=BN=128, LDS 2*16K + 3*16K = 80KB (2 blk/CU)
  hipFuncSetAttribute((const void*)k_gemm4<1, 4, 4, 2, 2>,
                      hipFuncAttributeMaxDynamicSharedMemorySize, 81920);

  k_cast<<<(S_LEN * HID) / (256 * 8), 256, 0, stream>>>(hs, Hh);
  k_trig<<<(S_LEN * 64) / 256, 256, 0, stream>>>(trig);
  k_wprep<<<40960, 256, 0, stream>>>(wq, wk, wv, wo, Wt, Wot);
  k_gemm4<0, 8, 3, 2, 4><<<dim3(NQKV / 192, S_LEN / 256), 512, 139264, stream>>>(
      Hh, Wt, Qrp, Krp, Vtp, trig, nullptr);
  k_attn<<<dim3(512), 256, 0, stream>>>(Qrp, Krp, Vtp, AO);
  k_gemm4<1, 4, 4, 2, 2><<<dim3(HID / 128, S_LEN / 128), 256, 81920, stream>>>(
      AO, Wot, nullptr, nullptr, nullptr, nullptr, out);
}

// Round 12
// 322.504 us; speedup vs baseline: 1.0966x; 1.0234x over previous
//
#include <hip/hip_runtime.h>

#define S_LEN 2048
#define HID 4096
#define NH 32
#define NKV 8
#define HD 128
#define KVW 1024       // NKV*HD
#define NQKV 6144      // HID + 2*KVW

typedef _Float16 f16;
typedef _Float16 f16x8 __attribute__((ext_vector_type(8)));
typedef _Float16 f16x4 __attribute__((ext_vector_type(4)));
typedef float f32x4 __attribute__((ext_vector_type(4)));
typedef float f32x16 __attribute__((ext_vector_type(16)));
typedef unsigned int u32;
typedef u32 u32x4 __attribute__((ext_vector_type(4)));

__device__ __forceinline__ void gll16(const void* g, void* lds) {
  __builtin_amdgcn_global_load_lds((const __attribute__((address_space(1))) void*)g,
                                   (__attribute__((address_space(3))) void*)lds, 16, 0, 0);
}

template<int N> __device__ __forceinline__ void vmwait() {
  if constexpr (N == 0) asm volatile("s_waitcnt vmcnt(0)" ::: "memory");
  else if constexpr (N == 2) asm volatile("s_waitcnt vmcnt(2)" ::: "memory");
  else if constexpr (N == 3) asm volatile("s_waitcnt vmcnt(3)" ::: "memory");
  else if constexpr (N == 4) asm volatile("s_waitcnt vmcnt(4)" ::: "memory");
  else if constexpr (N == 6) asm volatile("s_waitcnt vmcnt(6)" ::: "memory");
  else static_assert(N == 0, "add vmcnt case");
}

// ---------------- cast hidden f32 -> f16 ----------------
__global__ void k_cast(const float* __restrict__ src, f16* __restrict__ dst) {
  size_t i = ((size_t)blockIdx.x * blockDim.x + threadIdx.x) * 8;
  float4 a = *(const float4*)(src + i);
  float4 b = *(const float4*)(src + i + 4);
  f16x8 o = { (f16)a.x, (f16)a.y, (f16)a.z, (f16)a.w,
              (f16)b.x, (f16)b.y, (f16)b.z, (f16)b.w };
  *(f16x8*)(dst + i) = o;
}

// ---------------- RoPE trig table: [S][64] float4 = (cos(2i), cos(2i+1), sin(2i), sin(2i+1))
__global__ void k_trig(float4* __restrict__ trig) {
  int id = blockIdx.x * blockDim.x + threadIdx.x;
  int s = id >> 6, i = id & 63;
  int j0 = 2 * i, j1 = 2 * i + 1;
  float f0 = powf(10000.f, -(float)(j0 & 63) / 64.f);
  float f1 = powf(10000.f, -(float)(j1 & 63) / 64.f);
  float a0 = (float)s * f0, a1 = (float)s * f1;
  trig[id] = make_float4(cosf(a0), cosf(a1), sinf(a0), sinf(a1));
}

// ---------------- fused weight transpose+cast, all 4 matrices, one launch ----------------
__global__ __launch_bounds__(256) void k_wprep(
    const float* __restrict__ wq, const float* __restrict__ wk,
    const float* __restrict__ wv, const float* __restrict__ wo,
    f16* __restrict__ Wt, f16* __restrict__ Wot)
{
  __shared__ float tile[32][33];
  int bid = blockIdx.x;
  const float* src; f16* dst; int N; int r;
  if (bid < 16384)      { src = wq; dst = Wt;                          N = 4096; r = bid; }
  else if (bid < 20480) { src = wk; dst = Wt + (size_t)4096 * 4096;    N = 1024; r = bid - 16384; }
  else if (bid < 24576) { src = wv; dst = Wt + (size_t)5120 * 4096;    N = 1024; r = bid - 20480; }
  else                  { src = wo; dst = Wot;                         N = 4096; r = bid - 24576; }
  int tpr = N >> 5;
  int kb = (r / tpr) * 32, nb = (r % tpr) * 32;
  int t = threadIdx.x;
  {
    int kl = t >> 3, ng = t & 7;
    float4 v = *(const float4*)(src + (size_t)(kb + kl) * N + nb + ng * 4);
    tile[kl][ng * 4 + 0] = v.x; tile[kl][ng * 4 + 1] = v.y;
    tile[kl][ng * 4 + 2] = v.z; tile[kl][ng * 4 + 3] = v.w;
  }
  __syncthreads();
  {
    int nl = t >> 3, kg = t & 7;
    f16x4 o = { (f16)tile[kg * 4 + 0][nl], (f16)tile[kg * 4 + 1][nl],
                (f16)tile[kg * 4 + 2][nl], (f16)tile[kg * 4 + 3][nl] };
    *(f16x4*)(dst + (size_t)(nb + nl) * HID + kb + kg * 4) = o;
  }
}

// ---------------- loose-sync deep-prefetch GEMM + XCD-compact + 4-deep B ring ----------------
// R12 changes: (1) B ring 3 -> 4 slots; B(t+3) issued per tile so ~10 KB/wave of
// global_load_lds stay in flight (Little's-law staging-concurrency lever; was ~7).
// Steady-state fence vmcnt(BCALLS) keeps B(t+3) in flight across the barrier;
// tail (t>=NT-3) drains to 0. (2) gemm<1> now uses this same 8-wave structure.
// Everything else R11-verified: A dbuf t&1, stage A(t+1) per tile, ONE barrier/tile,
// granule swizzle g^(r&7) (0 conflicts), XCD-compact block mapping.
extern __shared__ char smem[];

template<int MODE, int MF, int NF, int WM, int WN>
__global__ __launch_bounds__(WM * WN * 64, 2) void k_gemm4(
    const f16* __restrict__ A, const f16* __restrict__ Bt,
    f16* __restrict__ Qr, f16* __restrict__ Kr, f16* __restrict__ Vt,
    const float4* __restrict__ trig, float* __restrict__ Cout)
{
  constexpr int NTHR = WM * WN * 64;
  constexpr int BM = WM * MF * 16;
  constexpr int BN = WN * NF * 16;
  constexpr int ABYTES = BM * 128;
  constexpr int BBYTES = BN * 128;
  constexpr int RPC = NTHR / 8;          // rows per staging call
  constexpr int ACALLS = BM / RPC;
  constexpr int BCALLS = BN / RPC;
  constexpr int NT = 64;                 // K=4096 / BK=64

  const int tid = threadIdx.x, ln = tid & 63, w = tid >> 6;
  const int la = ln & 15, lg = ln >> 4;
  const int wr = w / WN, wc = w % WN;

  // XCD-compact block mapping (grid.x assumed 32, grid.x*grid.y % 8 == 0)
  int bx, by;
  {
    int b = blockIdx.y * gridDim.x + blockIdx.x;
    int cx = gridDim.x >> 3;
    int xcd = b & 7, rr = b >> 3;
    bx = xcd * cx + (rr % cx);
    by = rr / cx;
  }
  const int m0 = by * BM, n0 = bx * BN;

  const char* asrc[ACALLS];
  const char* bsrc[BCALLS];
  int adst[ACALLS > BCALLS ? ACALLS : BCALLS];
#pragma unroll
  for (int c = 0; c < ACALLS; ++c) {
    int r = c * RPC + (tid >> 3);
    int g = (tid & 7) ^ (r & 7);
    asrc[c] = (const char*)A + ((size_t)(m0 + r) * HID + (size_t)g * 8) * 2;
    adst[c] = c * NTHR * 16 + tid * 16;
  }
#pragma unroll
  for (int c = 0; c < BCALLS; ++c) {
    int r = c * RPC + (tid >> 3);
    int g = (tid & 7) ^ (r & 7);
    bsrc[c] = (const char*)Bt + ((size_t)(n0 + (r >= BN ? r - BN : r)) * HID + (size_t)g * 8) * 2;
  }

  char* const Bbase = smem + 2 * ABYTES;
  f32x4 acc[MF][NF] = {};

  // prologue: A(0), B(0), B(1), B(2); fence keeps B(1),B(2) in flight
#pragma unroll
  for (int c = 0; c < ACALLS; ++c) gll16(asrc[c], smem + adst[c]);
#pragma unroll
  for (int c = 0; c < BCALLS; ++c) gll16(bsrc[c], Bbase + adst[c]);
#pragma unroll
  for (int c = 0; c < BCALLS; ++c) gll16(bsrc[c] + 128, Bbase + 1 * BBYTES + adst[c]);
#pragma unroll
  for (int c = 0; c < BCALLS; ++c) gll16(bsrc[c] + 256, Bbase + 2 * BBYTES + adst[c]);
  vmwait<2 * BCALLS>();
  __builtin_amdgcn_s_barrier();

  for (int t = 0; t < NT; ++t) {
    if (t + 1 < NT) {
      char* sa = smem + ((t + 1) & 1) * ABYTES;
#pragma unroll
      for (int c = 0; c < ACALLS; ++c) gll16(asrc[c] + (size_t)(t + 1) * 128, sa + adst[c]);
    }
    if (t + 3 < NT) {
      char* sb = Bbase + ((t + 3) & 3) * BBYTES;
#pragma unroll
      for (int c = 0; c < BCALLS; ++c) gll16(bsrc[c] + (size_t)(t + 3) * 128, sb + adst[c]);
    }
    const char* sa = smem + (t & 1) * ABYTES;
    const char* sb = Bbase + (t & 3) * BBYTES;
#pragma unroll
    for (int ks = 0; ks < 2; ++ks) {
      f16x8 af[MF], bf[NF];
#pragma unroll
      for (int i = 0; i < MF; ++i) {
        int rl = wr * MF * 16 + i * 16 + la;
        af[i] = *(const f16x8*)(sa + rl * 128 + (((ks * 4 + lg) ^ (rl & 7)) * 16));
      }
#pragma unroll
      for (int n = 0; n < NF; ++n) {
        int rb = wc * NF * 16 + n * 16 + la;
        bf[n] = *(const f16x8*)(sb + rb * 128 + (((ks * 4 + lg) ^ (rb & 7)) * 16));
      }
      __builtin_amdgcn_s_setprio(1);
#pragma unroll
      for (int i = 0; i < MF; ++i)
#pragma unroll
        for (int n = 0; n < NF; ++n)
          acc[i][n] = __builtin_amdgcn_mfma_f32_16x16x32_f16(af[i], bf[n], acc[i][n], 0, 0, 0);
      __builtin_amdgcn_s_setprio(0);
    }
    // fence: drain through A(t+1); keep B(t+3)'s BCALLS loads in flight.
    if (t < NT - 3)      vmwait<BCALLS>();
    else if (t < NT - 1) vmwait<0>();
    if (t < NT - 1) __builtin_amdgcn_s_barrier();
  }

  // ---- epilogue ----
#pragma unroll
  for (int mi = 0; mi < MF; ++mi) {
#pragma unroll
    for (int nf = 0; nf < NF; ++nf) {
      f32x4 fr = acc[mi][nf];
      int n = n0 + wc * NF * 16 + nf * 16 + la;
      int mr = m0 + wr * MF * 16 + mi * 16 + lg * 4;
      if (MODE == 0) {
        if (n < HID + KVW) {           // Q or K region -> RoPE
          int d = n & 127;
#pragma unroll
          for (int r = 0; r < 4; ++r) {
            float v = fr[r];
            float p = __shfl_xor(v, 1);
            float4 tc = trig[(size_t)(mr + r) * 64 + (d >> 1)];
            float cv = (d & 1) ? tc.y : tc.x;
            float sv = (d & 1) ? tc.w : tc.z;
            float o = v * cv + ((d & 1) ? p : -p) * sv;
            if (n < HID) Qr[(size_t)(mr + r) * HID + n] = (f16)o;
            else         Kr[(size_t)(mr + r) * KVW + (n - HID)] = (f16)o;
          }
        } else {                        // V region -> transposed store Vt[n][s]
          int nv = n - (HID + KVW);
          f16x4 o4 = { (f16)fr[0], (f16)fr[1], (f16)fr[2], (f16)fr[3] };
          *(f16x4*)(Vt + (size_t)nv * S_LEN + mr) = o4;
        }
      } else {
#pragma unroll
        for (int r = 0; r < 4; ++r)
          Cout[(size_t)(mr + r) * HID + n] = fr[r];
      }
    }
  }
}

// ---------------- flash attention, causal, GQA — swapped-QK^T 32x32 MFMA ----------------
#define KBYTES (64 * 128 * 2)   // 16KB K tile [64 kv][128 hd]
#define VBYTES (128 * 64 * 2)   // 16KB V tile [128 d][64 kv]

__global__ __launch_bounds__(256, 2) void k_attn(
    const f16* __restrict__ Qr, const f16* __restrict__ Kr, const f16* __restrict__ Vt,
    f16* __restrict__ AO)
{
  int bid = blockIdx.x;
  int h, c;
  if (bid < 256) { h = bid >> 3; c = bid & 7; }
  else           { int t = bid - 256; h = t >> 3; c = 15 - (t & 7); }
  const int hkv = h >> 2;
  const int q0c = c * 128;
  const int NT = 2 * c + 2;

  __shared__ char KV[2][KBYTES + VBYTES];

  const int tid = threadIdx.x;
  const int ln = tid & 63, w = tid >> 6;
  const int q = ln & 31;
  const int hi = ln >> 5;
  const int qg = q0c + w * 32 + q;

  size_t ksrc[4], vsrc[4];
  int kdo[4], vdo[4];
#pragma unroll
  for (int j = 0; j < 4; ++j) {
    int kc = w * 4 + j;
    int kr = kc * 4 + (ln >> 4);
    ksrc[j] = ((size_t)kr * KVW + hkv * HD) * 2 + (size_t)(((ln & 15) ^ (kr & 7)) * 16);
    kdo[j] = kc * 1024;
    int vc = w * 4 + j;
    int d = vc * 8 + (ln >> 3);
    vsrc[j] = ((size_t)(hkv * HD + d) * S_LEN) * 2 + (size_t)(((ln & 7) ^ (d & 7)) * 16);
    vdo[j] = KBYTES + vc * 1024;
  }

  f16x8 qf[8];
  {
    const f16* qrow = Qr + (size_t)qg * HID + h * HD + hi * 8;
#pragma unroll
    for (int ks = 0; ks < 8; ++ks) qf[ks] = *(const f16x8*)(qrow + ks * 16);
  }

  f32x16 ot[4] = {};
  float m2 = -3.0e38f, l = 0.f;
  const float K2 = 0.12753256471f;  // log2(e)/sqrt(128)

  int buf = 0;
#pragma unroll
  for (int j = 0; j < 4; ++j) {
    gll16((const char*)Kr + ksrc[j], &KV[0][kdo[j]]);
    gll16((const char*)Vt + vsrc[j], &KV[0][vdo[j]]);
  }

  for (int jt = 0; jt < NT; ++jt) {
    __syncthreads();
    if (jt + 1 < NT) {
      size_t ko = (size_t)(jt + 1) * 64 * KVW * 2;
      size_t vo = (size_t)(jt + 1) * 64 * 2;
#pragma unroll
      for (int j = 0; j < 4; ++j) {
        gll16((const char*)Kr + ksrc[j] + ko, &KV[buf ^ 1][kdo[j]]);
        gll16((const char*)Vt + vsrc[j] + vo, &KV[buf ^ 1][vdo[j]]);
      }
    }
    const int j0 = jt * 64;
    if (j0 <= q0c + w * 32 + 31) {
      const f16* Kb = (const f16*)&KV[buf][0];
      const f16* Vb = (const f16*)&KV[buf][KBYTES];
      f32x16 s0 = {}, s1 = {};
#pragma unroll
      for (int ks = 0; ks < 8; ++ks) {
        int cc = ((ks * 2 + hi) ^ (q & 7)) * 8;
        f16x8 k0 = *(const f16x8*)(Kb + q * 128 + cc);
        f16x8 k1 = *(const f16x8*)(Kb + (q + 32) * 128 + cc);
        s0 = __builtin_amdgcn_mfma_f32_32x32x16_f16(k0, qf[ks], s0, 0, 0, 0);
        s1 = __builtin_amdgcn_mfma_f32_32x32x16_f16(k1, qf[ks], s1, 0, 0, 0);
      }
      const bool nm = (j0 + 63 > q0c + w * 32);
      float p0[16], p1[16];
      float mx = -3.0e38f;
#pragma unroll
      for (int r = 0; r < 16; ++r) {
        float a = s0[r], b = s1[r];
        if (nm) {
          int kvb = j0 + (r & 3) + 8 * (r >> 2) + 4 * hi;
          if (kvb > qg) a = -3.0e38f;
          if (kvb + 32 > qg) b = -3.0e38f;
        }
        p0[r] = a; p1[r] = b;
        mx = fmaxf(mx, fmaxf(a, b));
      }
      mx = fmaxf(mx, __shfl_xor(mx, 32));
      float m2c = mx * K2;
      int defer = (m2c <= m2 + 11.0f);
      if (!__all(defer)) {
        float m2n = fmaxf(m2, m2c);
        float corr = exp2f(m2 - m2n);
        m2 = m2n; l *= corr;
#pragma unroll
        for (int t = 0; t < 4; ++t)
#pragma unroll
          for (int r = 0; r < 16; ++r) ot[t][r] *= corr;
      }
      float sum = 0.f;
#pragma unroll
      for (int r = 0; r < 16; ++r) {
        p0[r] = exp2f(__builtin_fmaf(p0[r], K2, -m2));
        p1[r] = exp2f(__builtin_fmaf(p1[r], K2, -m2));
        sum += p0[r] + p1[r];
      }
      l += sum + __shfl_xor(sum, 32);
      u32 pw0[8], pw1[8];
#pragma unroll
      for (int t = 0; t < 8; ++t) {
        pw0[t] = __builtin_bit_cast(u32, __builtin_amdgcn_cvt_pkrtz(p0[2 * t], p0[2 * t + 1]));
        pw1[t] = __builtin_bit_cast(u32, __builtin_amdgcn_cvt_pkrtz(p1[2 * t], p1[2 * t + 1]));
      }
      f16x8 pf[4];
#pragma unroll
      for (int ch = 0; ch < 2; ++ch) {
        const u32* pw = ch ? pw1 : pw0;
        u32 sx[8];
#pragma unroll
        for (int t = 0; t < 8; ++t) sx[t] = (u32)__shfl_xor((int)pw[t], 32);
        u32x4 fa = { hi ? sx[2] : pw[0], hi ? sx[3] : pw[1],
                     hi ? pw[2] : sx[0], hi ? pw[3] : sx[1] };
        u32x4 fb = { hi ? sx[6] : pw[4], hi ? sx[7] : pw[5],
                     hi ? pw[6] : sx[4], hi ? pw[7] : sx[5] };
        pf[ch * 2 + 0] = __builtin_bit_cast(f16x8, fa);
        pf[ch * 2 + 1] = __builtin_bit_cast(f16x8, fb);
      }
#pragma unroll
      for (int dt = 0; dt < 4; ++dt) {
        int d = dt * 32 + q;
#pragma unroll
        for (int f = 0; f < 4; ++f) {
          f16x8 vf = *(const f16x8*)(Vb + d * 64 + (((f * 2 + hi) ^ (q & 7)) * 8));
          ot[dt] = __builtin_amdgcn_mfma_f32_32x32x16_f16(vf, pf[f], ot[dt], 0, 0, 0);
        }
      }
    }
    buf ^= 1;
  }

  __syncthreads();
  char* scr = &KV[0][0] + w * 8192;
  float inv = 1.f / l;
#pragma unroll
  for (int dt = 0; dt < 4; ++dt) {
#pragma unroll
    for (int rg = 0; rg < 4; ++rg) {
      u32 wa = __builtin_bit_cast(u32, __builtin_amdgcn_cvt_pkrtz(ot[dt][rg * 4 + 0] * inv, ot[dt][rg * 4 + 1] * inv));
      u32 wb = __builtin_bit_cast(u32, __builtin_amdgcn_cvt_pkrtz(ot[dt][rg * 4 + 2] * inv, ot[dt][rg * 4 + 3] * inv));
      int byte = q * 256 + (((dt * 4 + rg) ^ (q & 7)) * 16) + hi * 8;
      u32* p = (u32*)(scr + byte);
      p[0] = wa; p[1] = wb;
    }
  }
  asm volatile("s_waitcnt lgkmcnt(0)" ::: "memory");
#pragma unroll
  for (int ps = 0; ps < 8; ++ps) {
    int qr = ps * 4 + (ln >> 4);
    int ck = (ln & 15) ^ (qr & 7);
    f16x8 v = *(const f16x8*)(scr + qr * 256 + ck * 16);
    *(f16x8*)(AO + (size_t)(q0c + w * 32 + qr) * HID + h * HD + (ln & 15) * 8) = v;
  }
}

extern "C" void kernel_launch(void* const* d_in, const int* in_sizes, int n_in,
                              void* d_out, int out_size, void* d_ws, size_t ws_size,
                              hipStream_t stream) {
  const float* hs = (const float*)d_in[0];
  // d_in[1] = attention_mask (pure causal; handled analytically)
  const float* wq = (const float*)d_in[2];
  const float* wk = (const float*)d_in[3];
  const float* wv = (const float*)d_in[4];
  const float* wo = (const float*)d_in[5];
  float* out = (float*)d_out;

  char* ws = (char*)d_ws;
  size_t off = 0;
  auto alloc = [&](size_t b) { char* p = ws + off; off += (b + 255) & ~(size_t)255; return p; };
  f16* Hh   = (f16*)alloc((size_t)S_LEN * HID * 2);
  f16* Wt   = (f16*)alloc((size_t)NQKV * HID * 2);
  float4* trig = (float4*)alloc((size_t)S_LEN * 64 * sizeof(float4));
  f16* Qrp  = (f16*)alloc((size_t)S_LEN * HID * 2);
  f16* Krp  = (f16*)alloc((size_t)S_LEN * KVW * 2);
  f16* Vtp  = (f16*)alloc((size_t)KVW * S_LEN * 2);
  f16* AO   = (f16*)alloc((size_t)S_LEN * HID * 2);
  f16* Wot  = (f16*)alloc((size_t)HID * HID * 2);

  // gemm<0>: 8 waves 2x4, wave 128x48, BM=256 BN=192, LDS 2*32K + 4*24K = 160 KiB
  hipFuncSetAttribute((const void*)k_gemm4<0, 8, 3, 2, 4>,
                      hipFuncAttributeMaxDynamicSharedMemorySize, 163840);
  // gemm<1>: 8 waves 2x4, wave 128x32, BM=256 BN=128, LDS 2*32K + 4*16K = 128 KiB
  hipFuncSetAttribute((const void*)k_gemm4<1, 8, 2, 2, 4>,
                      hipFuncAttributeMaxDynamicSharedMemorySize, 131072);

  k_cast<<<(S_LEN * HID) / (256 * 8), 256, 0, stream>>>(hs, Hh);
  k_trig<<<(S_LEN * 64) / 256, 256, 0, stream>>>(trig);
  k_wprep<<<40960, 256, 0, stream>>>(wq, wk, wv, wo, Wt, Wot);
  k_gemm4<0, 8, 3, 2, 4><<<dim3(NQKV / 192, S_LEN / 256), 512, 163840, stream>>>(
      Hh, Wt, Qrp, Krp, Vtp, trig, nullptr);
  k_attn<<<dim3(512), 256, 0, stream>>>(Qrp, Krp, Vtp, AO);
  k_gemm4<1, 8, 2, 2, 4><<<dim3(HID / 128, S_LEN / 256), 512, 131072, stream>>>(
      AO, Wot, nullptr, nullptr, nullptr, nullptr, out);
}